// Round 15
// baseline (96.924 us; speedup 1.0000x reference)
//
#include <hip/hip_runtime.h>

// Instant-NGP style hash grid interpolation.
// x: [N, 3] f32 in [0,1), emb: [524288, 8] f32, out: [N, 8] f32.
//
// Round 15: 2 points per thread. R14 analysis: gather runs 0.60 req/cy/ch,
// and rate DROPPED R6->R8 as requests fell => latency-bound via Little's law
// (22 waves x 4-8 outstanding ~= 150 in flight @ ~250cy L2 latency = 0.6
// req/cy/CU, matching measurement). Doubling pinned in-flight loads per wave
// (two points' gathers before one vmcnt(0)) should raise throughput if the
// outstanding-window is the binder; null => channel-rate wall (roofline).
// Prep unchanged from R14 (1024-block absmax + fused-reduce quantize).

#define HASHMAP_SIZE 524288
#define HASHMAP_MASK 524287u   // 2^19 - 1
#define RESOLUTION   128.0f
#define PRIME1       2654435761u
#define PRIME2       805459861u

typedef float f32x4 __attribute__((ext_vector_type(4)));
typedef int   i32x2 __attribute__((ext_vector_type(2)));
typedef int   i32x4 __attribute__((ext_vector_type(4)));

#define NRED_BLOCKS 1024   // stage1 grid; 1024*256*4 float4 == 16MB exactly

__device__ __forceinline__ int pack4(float4 v, float rs) {
    int b0 = __float2int_rn(v.x * rs), b1 = __float2int_rn(v.y * rs);
    int b2 = __float2int_rn(v.z * rs), b3 = __float2int_rn(v.w * rs);
    return (int)((b0 & 0xff) | ((b1 & 0xff) << 8) |
                 ((b2 & 0xff) << 16) | ((unsigned)b3 << 24));
}

// ---- stage 1: per-block absmax over emb (one exact pass, 4 f32x4/thread) ----
__global__ __launch_bounds__(256) void absmax_stage1(
    const float* __restrict__ emb, float* __restrict__ blockmax)
{
    __shared__ float sm[256];
    int tid = threadIdx.x;
    int t = blockIdx.x * 256 + tid;
    const f32x4* e4 = reinterpret_cast<const f32x4*>(emb);
    float m = 0.f;
#pragma unroll
    for (int k = 0; k < 4; ++k) {
        f32x4 v = e4[t + k * (NRED_BLOCKS * 256)];
        m = fmaxf(m, fmaxf(fmaxf(fabsf(v.x), fabsf(v.y)),
                           fmaxf(fabsf(v.z), fabsf(v.w))));
    }
    sm[tid] = m;
    __syncthreads();
    for (int s = 128; s > 0; s >>= 1) {
        if (tid < s) sm[tid] = fmaxf(sm[tid], sm[tid + s]);
        __syncthreads();
    }
    if (tid == 0) blockmax[blockIdx.x] = sm[0];
}

// ---- quantize (+ final reduce of 1024 partials): f32 rows -> int8 rows ----
__global__ __launch_bounds__(256) void quantize_fused(
    const float* __restrict__ emb, const float* __restrict__ blockmax,
    i32x2* __restrict__ tab, float* __restrict__ scalef)
{
    __shared__ float sm[256];
    int tid = threadIdx.x;
    float m = fmaxf(fmaxf(blockmax[tid],       blockmax[tid + 256]),
                    fmaxf(blockmax[tid + 512], blockmax[tid + 768]));
    sm[tid] = m;
    __syncthreads();
    for (int s = 128; s > 0; s >>= 1) {
        if (tid < s) sm[tid] = fmaxf(sm[tid], sm[tid + s]);
        __syncthreads();
    }
    float sc = (sm[0] > 0.f) ? sm[0] : 1.0f;
    if (blockIdx.x == 0 && tid == 0) scalef[0] = sc;

    int r = blockIdx.x * 256 + tid;
    if (r >= HASHMAP_SIZE) return;
    float rs = 127.0f / sc;
    const float4* src = reinterpret_cast<const float4*>(emb) + 2 * r;
    i32x2 o;
    o.x = pack4(src[0], rs);
    o.y = pack4(src[1], rs);
    __builtin_nontemporal_store(o, &tab[r]);   // clean lines -> L3, not dirty L2
}

__device__ __forceinline__ float sb(int v, int sh) {
    // sign-extended byte -> float
    return (float)((int)((unsigned)v << (24 - sh)) >> 24);
}

// ---- gather: 2 points/thread, all loads pinned in flight before one wait ----
__global__ __launch_bounds__(256) void hashgrid_i8_x2(
    const float* __restrict__ x,
    const i32x2* __restrict__ tab,
    const float* __restrict__ scale,
    float* __restrict__ out,
    int n)
{
    int t = blockIdx.x * blockDim.x + threadIdx.x;
    int iA = 2 * t;
    int iB = 2 * t + 1;
    if (iA >= n) return;
    bool hasB = (iB < n);

    // 6 contiguous floats per thread (24B) — coalesced.
    float a0 = __builtin_nontemporal_load(x + 6 * t + 0);
    float a1 = __builtin_nontemporal_load(x + 6 * t + 1);
    float a2 = __builtin_nontemporal_load(x + 6 * t + 2);
    float b0 = 0.f, b1 = 0.f, b2 = 0.f;
    if (hasB) {
        b0 = __builtin_nontemporal_load(x + 6 * t + 3);
        b1 = __builtin_nontemporal_load(x + 6 * t + 4);
        b2 = __builtin_nontemporal_load(x + 6 * t + 5);
    }

    // ---- point A setup ----
    float Ar0 = a0 * RESOLUTION, Ar1 = a1 * RESOLUTION, Ar2 = a2 * RESOLUTION;
    float Afl0 = floorf(Ar0), Afl1 = floorf(Ar1), Afl2 = floorf(Ar2);
    float Af0 = Ar0 - Afl0, Af1 = Ar1 - Afl1, Af2 = Ar2 - Afl2;
    unsigned Au0 = (unsigned)(int)Afl0;
    unsigned Au1 = (unsigned)(int)Afl1;
    unsigned Au2 = (unsigned)(int)Afl2;
    unsigned Ah1a = Au1 * PRIME1, Ah1b = (Au1 + 1u) * PRIME1;
    unsigned Ah2a = Au2 * PRIME2, Ah2b = (Au2 + 1u) * PRIME2;
    bool Aeven = ((Au0 & 1u) == 0u);

    // ---- point B setup ----
    float Br0 = b0 * RESOLUTION, Br1 = b1 * RESOLUTION, Br2 = b2 * RESOLUTION;
    float Bfl0 = floorf(Br0), Bfl1 = floorf(Br1), Bfl2 = floorf(Br2);
    float Bf0 = Br0 - Bfl0, Bf1 = Br1 - Bfl1, Bf2 = Br2 - Bfl2;
    unsigned Bu0 = (unsigned)(int)Bfl0;
    unsigned Bu1 = (unsigned)(int)Bfl1;
    unsigned Bu2 = (unsigned)(int)Bfl2;
    unsigned Bh1a = Bu1 * PRIME1, Bh1b = (Bu1 + 1u) * PRIME1;
    unsigned Bh2a = Bu2 * PRIME2, Bh2b = (Bu2 + 1u) * PRIME2;
    bool Beven = ((Bu0 & 1u) == 0u);

    // ---- phase 1: issue ALL loads for both points, then one waitcnt ----
    i32x2 qvA[8]; i32x4 pvA[4]; unsigned rlA[4];
    i32x2 qvB[8]; i32x4 pvB[4]; unsigned rlB[4];

    if (Aeven) {
#pragma unroll
        for (int cp = 0; cp < 4; ++cp) {
            unsigned t1 = (cp & 1) ? Ah1b : Ah1a;
            unsigned t2 = (cp & 2) ? Ah2b : Ah2a;
            unsigned r  = (Au0 ^ t1 ^ t2) & HASHMAP_MASK;
            rlA[cp] = r;
            const i32x2* p = tab + (r & ~1u);
            asm volatile("global_load_dwordx4 %0, %1, off"
                         : "=&v"(pvA[cp]) : "v"(p));
        }
    } else {
#pragma unroll
        for (int c = 0; c < 8; ++c) {
            unsigned t0 = (c & 1) ? (Au0 + 1u) : Au0;
            unsigned t1 = (c & 2) ? Ah1b : Ah1a;
            unsigned t2 = (c & 4) ? Ah2b : Ah2a;
            unsigned r  = (t0 ^ t1 ^ t2) & HASHMAP_MASK;
            const i32x2* p = tab + r;
            asm volatile("global_load_dwordx2 %0, %1, off"
                         : "=&v"(qvA[c]) : "v"(p));
        }
    }
    if (hasB) {
        if (Beven) {
#pragma unroll
            for (int cp = 0; cp < 4; ++cp) {
                unsigned t1 = (cp & 1) ? Bh1b : Bh1a;
                unsigned t2 = (cp & 2) ? Bh2b : Bh2a;
                unsigned r  = (Bu0 ^ t1 ^ t2) & HASHMAP_MASK;
                rlB[cp] = r;
                const i32x2* p = tab + (r & ~1u);
                asm volatile("global_load_dwordx4 %0, %1, off"
                             : "=&v"(pvB[cp]) : "v"(p));
            }
        } else {
#pragma unroll
            for (int c = 0; c < 8; ++c) {
                unsigned t0 = (c & 1) ? (Bu0 + 1u) : Bu0;
                unsigned t1 = (c & 2) ? Bh1b : Bh1a;
                unsigned t2 = (c & 4) ? Bh2b : Bh2a;
                unsigned r  = (t0 ^ t1 ^ t2) & HASHMAP_MASK;
                const i32x2* p = tab + r;
                asm volatile("global_load_dwordx2 %0, %1, off"
                             : "=&v"(qvB[c]) : "v"(p));
            }
        }
    }
    asm volatile("s_waitcnt vmcnt(0)" ::: "memory");
    __builtin_amdgcn_sched_barrier(0);

    float os = scale[0] * (1.0f / 127.0f);

    // ---- phase 2, point A ----
    if (Aeven) {
#pragma unroll
        for (int cp = 0; cp < 4; ++cp) {
            bool swap = (rlA[cp] & 1u) != 0u;
            i32x2 lo; lo.x = pvA[cp].x; lo.y = pvA[cp].y;
            i32x2 hi; hi.x = pvA[cp].z; hi.y = pvA[cp].w;
            qvA[2 * cp + 0] = swap ? hi : lo;
            qvA[2 * cp + 1] = swap ? lo : hi;
        }
    }
    {
        float g0 = 1.0f - Af0, g1 = 1.0f - Af1, g2 = 1.0f - Af2;
        float acc0 = 0.f, acc1 = 0.f, acc2 = 0.f, acc3 = 0.f;
        float acc4 = 0.f, acc5 = 0.f, acc6 = 0.f, acc7 = 0.f;
#pragma unroll
        for (int cp = 0; cp < 4; ++cp) {
            float w12 = ((cp & 1) ? Af1 : g1) * ((cp & 2) ? Af2 : g2);
#pragma unroll
            for (int c0 = 0; c0 < 2; ++c0) {
                float w = w12 * (c0 ? Af0 : g0);
                int a = qvA[2 * cp + c0].x, b = qvA[2 * cp + c0].y;
                acc0 += w * sb(a, 0);  acc1 += w * sb(a, 8);
                acc2 += w * sb(a, 16); acc3 += w * sb(a, 24);
                acc4 += w * sb(b, 0);  acc5 += w * sb(b, 8);
                acc6 += w * sb(b, 16); acc7 += w * sb(b, 24);
            }
        }
        f32x4* o = reinterpret_cast<f32x4*>(out) + (size_t)iA * 2u;
        f32x4 o0 = {acc0 * os, acc1 * os, acc2 * os, acc3 * os};
        f32x4 o1 = {acc4 * os, acc5 * os, acc6 * os, acc7 * os};
        __builtin_nontemporal_store(o0, o);
        __builtin_nontemporal_store(o1, o + 1);
    }

    // ---- phase 2, point B ----
    if (hasB) {
        if (Beven) {
#pragma unroll
            for (int cp = 0; cp < 4; ++cp) {
                bool swap = (rlB[cp] & 1u) != 0u;
                i32x2 lo; lo.x = pvB[cp].x; lo.y = pvB[cp].y;
                i32x2 hi; hi.x = pvB[cp].z; hi.y = pvB[cp].w;
                qvB[2 * cp + 0] = swap ? hi : lo;
                qvB[2 * cp + 1] = swap ? lo : hi;
            }
        }
        float g0 = 1.0f - Bf0, g1 = 1.0f - Bf1, g2 = 1.0f - Bf2;
        float acc0 = 0.f, acc1 = 0.f, acc2 = 0.f, acc3 = 0.f;
        float acc4 = 0.f, acc5 = 0.f, acc6 = 0.f, acc7 = 0.f;
#pragma unroll
        for (int cp = 0; cp < 4; ++cp) {
            float w12 = ((cp & 1) ? Bf1 : g1) * ((cp & 2) ? Bf2 : g2);
#pragma unroll
            for (int c0 = 0; c0 < 2; ++c0) {
                float w = w12 * (c0 ? Bf0 : g0);
                int a = qvB[2 * cp + c0].x, b = qvB[2 * cp + c0].y;
                acc0 += w * sb(a, 0);  acc1 += w * sb(a, 8);
                acc2 += w * sb(a, 16); acc3 += w * sb(a, 24);
                acc4 += w * sb(b, 0);  acc5 += w * sb(b, 8);
                acc6 += w * sb(b, 16); acc7 += w * sb(b, 24);
            }
        }
        f32x4* o = reinterpret_cast<f32x4*>(out) + (size_t)iB * 2u;
        f32x4 o0 = {acc0 * os, acc1 * os, acc2 * os, acc3 * os};
        f32x4 o1 = {acc4 * os, acc5 * os, acc6 * os, acc7 * os};
        __builtin_nontemporal_store(o0, o);
        __builtin_nontemporal_store(o1, o + 1);
    }
}

// ---- fallback: direct fp32 path (if d_ws too small) ----
__global__ __launch_bounds__(256) void hashgrid_fp32_kernel(
    const float* __restrict__ x,
    const float* __restrict__ emb,
    float* __restrict__ out,
    int n)
{
    int i = blockIdx.x * blockDim.x + threadIdx.x;
    if (i >= n) return;

    float x0 = x[i * 3 + 0], x1 = x[i * 3 + 1], x2 = x[i * 3 + 2];
    float xr0 = x0 * RESOLUTION, xr1 = x1 * RESOLUTION, xr2 = x2 * RESOLUTION;
    float fl0 = floorf(xr0), fl1 = floorf(xr1), fl2 = floorf(xr2);
    float f0 = xr0 - fl0, f1 = xr1 - fl1, f2 = xr2 - fl2;
    unsigned u0 = (unsigned)(int)fl0, u1 = (unsigned)(int)fl1, u2 = (unsigned)(int)fl2;

    unsigned h0a = u0,          h0b = u0 + 1u;
    unsigned h1a = u1 * PRIME1, h1b = (u1 + 1u) * PRIME1;
    unsigned h2a = u2 * PRIME2, h2b = (u2 + 1u) * PRIME2;

    float g0 = 1.0f - f0, g1 = 1.0f - f1, g2 = 1.0f - f2;
    float acc0 = 0.f, acc1 = 0.f, acc2 = 0.f, acc3 = 0.f;
    float acc4 = 0.f, acc5 = 0.f, acc6 = 0.f, acc7 = 0.f;

#pragma unroll
    for (int c = 0; c < 8; ++c) {
        unsigned h = (((c & 1) ? h0b : h0a) ^
                      ((c & 2) ? h1b : h1a) ^
                      ((c & 4) ? h2b : h2a)) & HASHMAP_MASK;
        float w = ((c & 1) ? f0 : g0) *
                  ((c & 2) ? f1 : g1) *
                  ((c & 4) ? f2 : g2);
        const float4* e = reinterpret_cast<const float4*>(emb) + (h << 1);
        float4 e0 = e[0];
        float4 e1 = e[1];
        acc0 += w * e0.x; acc1 += w * e0.y; acc2 += w * e0.z; acc3 += w * e0.w;
        acc4 += w * e1.x; acc5 += w * e1.y; acc6 += w * e1.z; acc7 += w * e1.w;
    }

    float4* o = reinterpret_cast<float4*>(out) + (size_t)i * 2u;
    o[0] = make_float4(acc0, acc1, acc2, acc3);
    o[1] = make_float4(acc4, acc5, acc6, acc7);
}

extern "C" void kernel_launch(void* const* d_in, const int* in_sizes, int n_in,
                              void* d_out, int out_size, void* d_ws, size_t ws_size,
                              hipStream_t stream) {
    const float* x   = (const float*)d_in[0];
    const float* emb = (const float*)d_in[1];
    float* out = (float*)d_out;

    int n = in_sizes[0] / 3;  // x has N*3 elements

    // ws layout: [0, 4MB) int8 table | blockmax[1024] | scalef
    size_t tab_bytes = (size_t)HASHMAP_SIZE * 8u;   // 4 MB
    size_t bm_off    = tab_bytes;
    size_t sf_off    = tab_bytes + NRED_BLOCKS * sizeof(float);
    size_t need      = sf_off + sizeof(float);

    if (ws_size >= need) {
        i32x2* tab      = (i32x2*)d_ws;
        float* blockmax = (float*)((char*)d_ws + bm_off);
        float* scalef   = (float*)((char*)d_ws + sf_off);

        absmax_stage1<<<NRED_BLOCKS, 256, 0, stream>>>(emb, blockmax);
        int qgrid = HASHMAP_SIZE / 256;   // 2048
        quantize_fused<<<qgrid, 256, 0, stream>>>(emb, blockmax, tab, scalef);
        int npairs = (n + 1) / 2;
        int ggrid = (npairs + 255) / 256;
        hashgrid_i8_x2<<<ggrid, 256, 0, stream>>>(x, tab, scalef, out, n);
    } else {
        int grid = (n + 255) / 256;
        hashgrid_fp32_kernel<<<grid, 256, 0, stream>>>(x, emb, out, n);
    }
}

// Round 17
// 96.709 us; speedup vs baseline: 1.0022x; 1.0022x over previous
//
#include <hip/hip_runtime.h>

// Instant-NGP style hash grid interpolation.
// x: [N, 3] f32 in [0,1), emb: [524288, 8] f32, out: [N, 8] f32.
//
// Round 17: R15 VERBATIM except __launch_bounds__(256,2) on the x2 gather.
// R15 passed correctness but spilled (VGPR capped 48, WRITE 67->117MB) under
// the default occupancy target, so the 2x in-flight window never material-
// ized. (256,2) grants a 128-VGPR budget (~70 needed) -> no spill, 4-5
// waves/SIMD each with 12 pinned loads in flight. R16's asm/branch rewrite
// is abandoned (phi-copy-before-waitcnt hazard on asm loads).
// Prep unchanged from R14 (1024-block absmax + fused-reduce quantize).

#define HASHMAP_SIZE 524288
#define HASHMAP_MASK 524287u   // 2^19 - 1
#define RESOLUTION   128.0f
#define PRIME1       2654435761u
#define PRIME2       805459861u

typedef float f32x4 __attribute__((ext_vector_type(4)));
typedef int   i32x2 __attribute__((ext_vector_type(2)));
typedef int   i32x4 __attribute__((ext_vector_type(4)));

#define NRED_BLOCKS 1024   // stage1 grid; 1024*256*4 float4 == 16MB exactly

__device__ __forceinline__ int pack4(float4 v, float rs) {
    int b0 = __float2int_rn(v.x * rs), b1 = __float2int_rn(v.y * rs);
    int b2 = __float2int_rn(v.z * rs), b3 = __float2int_rn(v.w * rs);
    return (int)((b0 & 0xff) | ((b1 & 0xff) << 8) |
                 ((b2 & 0xff) << 16) | ((unsigned)b3 << 24));
}

// ---- stage 1: per-block absmax over emb (one exact pass, 4 f32x4/thread) ----
__global__ __launch_bounds__(256) void absmax_stage1(
    const float* __restrict__ emb, float* __restrict__ blockmax)
{
    __shared__ float sm[256];
    int tid = threadIdx.x;
    int t = blockIdx.x * 256 + tid;
    const f32x4* e4 = reinterpret_cast<const f32x4*>(emb);
    float m = 0.f;
#pragma unroll
    for (int k = 0; k < 4; ++k) {
        f32x4 v = e4[t + k * (NRED_BLOCKS * 256)];
        m = fmaxf(m, fmaxf(fmaxf(fabsf(v.x), fabsf(v.y)),
                           fmaxf(fabsf(v.z), fabsf(v.w))));
    }
    sm[tid] = m;
    __syncthreads();
    for (int s = 128; s > 0; s >>= 1) {
        if (tid < s) sm[tid] = fmaxf(sm[tid], sm[tid + s]);
        __syncthreads();
    }
    if (tid == 0) blockmax[blockIdx.x] = sm[0];
}

// ---- quantize (+ final reduce of 1024 partials): f32 rows -> int8 rows ----
__global__ __launch_bounds__(256) void quantize_fused(
    const float* __restrict__ emb, const float* __restrict__ blockmax,
    i32x2* __restrict__ tab, float* __restrict__ scalef)
{
    __shared__ float sm[256];
    int tid = threadIdx.x;
    float m = fmaxf(fmaxf(blockmax[tid],       blockmax[tid + 256]),
                    fmaxf(blockmax[tid + 512], blockmax[tid + 768]));
    sm[tid] = m;
    __syncthreads();
    for (int s = 128; s > 0; s >>= 1) {
        if (tid < s) sm[tid] = fmaxf(sm[tid], sm[tid + s]);
        __syncthreads();
    }
    float sc = (sm[0] > 0.f) ? sm[0] : 1.0f;
    if (blockIdx.x == 0 && tid == 0) scalef[0] = sc;

    int r = blockIdx.x * 256 + tid;
    if (r >= HASHMAP_SIZE) return;
    float rs = 127.0f / sc;
    const float4* src = reinterpret_cast<const float4*>(emb) + 2 * r;
    i32x2 o;
    o.x = pack4(src[0], rs);
    o.y = pack4(src[1], rs);
    __builtin_nontemporal_store(o, &tab[r]);
}

__device__ __forceinline__ float sb(int v, int sh) {
    // sign-extended byte -> float
    return (float)((int)((unsigned)v << (24 - sh)) >> 24);
}

// ---- gather: 2 points/thread, all loads pinned in flight before one wait ----
__global__ __launch_bounds__(256, 2) void hashgrid_i8_x2(
    const float* __restrict__ x,
    const i32x2* __restrict__ tab,
    const float* __restrict__ scale,
    float* __restrict__ out,
    int n)
{
    int t = blockIdx.x * blockDim.x + threadIdx.x;
    int iA = 2 * t;
    int iB = 2 * t + 1;
    if (iA >= n) return;
    bool hasB = (iB < n);

    // 6 contiguous floats per thread (24B) — coalesced.
    float a0 = __builtin_nontemporal_load(x + 6 * t + 0);
    float a1 = __builtin_nontemporal_load(x + 6 * t + 1);
    float a2 = __builtin_nontemporal_load(x + 6 * t + 2);
    float b0 = 0.f, b1 = 0.f, b2 = 0.f;
    if (hasB) {
        b0 = __builtin_nontemporal_load(x + 6 * t + 3);
        b1 = __builtin_nontemporal_load(x + 6 * t + 4);
        b2 = __builtin_nontemporal_load(x + 6 * t + 5);
    }

    // ---- point A setup ----
    float Ar0 = a0 * RESOLUTION, Ar1 = a1 * RESOLUTION, Ar2 = a2 * RESOLUTION;
    float Afl0 = floorf(Ar0), Afl1 = floorf(Ar1), Afl2 = floorf(Ar2);
    float Af0 = Ar0 - Afl0, Af1 = Ar1 - Afl1, Af2 = Ar2 - Afl2;
    unsigned Au0 = (unsigned)(int)Afl0;
    unsigned Au1 = (unsigned)(int)Afl1;
    unsigned Au2 = (unsigned)(int)Afl2;
    unsigned Ah1a = Au1 * PRIME1, Ah1b = (Au1 + 1u) * PRIME1;
    unsigned Ah2a = Au2 * PRIME2, Ah2b = (Au2 + 1u) * PRIME2;
    bool Aeven = ((Au0 & 1u) == 0u);

    // ---- point B setup ----
    float Br0 = b0 * RESOLUTION, Br1 = b1 * RESOLUTION, Br2 = b2 * RESOLUTION;
    float Bfl0 = floorf(Br0), Bfl1 = floorf(Br1), Bfl2 = floorf(Br2);
    float Bf0 = Br0 - Bfl0, Bf1 = Br1 - Bfl1, Bf2 = Br2 - Bfl2;
    unsigned Bu0 = (unsigned)(int)Bfl0;
    unsigned Bu1 = (unsigned)(int)Bfl1;
    unsigned Bu2 = (unsigned)(int)Bfl2;
    unsigned Bh1a = Bu1 * PRIME1, Bh1b = (Bu1 + 1u) * PRIME1;
    unsigned Bh2a = Bu2 * PRIME2, Bh2b = (Bu2 + 1u) * PRIME2;
    bool Beven = ((Bu0 & 1u) == 0u);

    // ---- phase 1: issue ALL loads for both points, then one waitcnt ----
    i32x2 qvA[8]; i32x4 pvA[4]; unsigned rlA[4];
    i32x2 qvB[8]; i32x4 pvB[4]; unsigned rlB[4];

    if (Aeven) {
#pragma unroll
        for (int cp = 0; cp < 4; ++cp) {
            unsigned t1 = (cp & 1) ? Ah1b : Ah1a;
            unsigned t2 = (cp & 2) ? Ah2b : Ah2a;
            unsigned r  = (Au0 ^ t1 ^ t2) & HASHMAP_MASK;
            rlA[cp] = r;
            const i32x2* p = tab + (r & ~1u);
            asm volatile("global_load_dwordx4 %0, %1, off"
                         : "=&v"(pvA[cp]) : "v"(p));
        }
    } else {
#pragma unroll
        for (int c = 0; c < 8; ++c) {
            unsigned t0 = (c & 1) ? (Au0 + 1u) : Au0;
            unsigned t1 = (c & 2) ? Ah1b : Ah1a;
            unsigned t2 = (c & 4) ? Ah2b : Ah2a;
            unsigned r  = (t0 ^ t1 ^ t2) & HASHMAP_MASK;
            const i32x2* p = tab + r;
            asm volatile("global_load_dwordx2 %0, %1, off"
                         : "=&v"(qvA[c]) : "v"(p));
        }
    }
    if (hasB) {
        if (Beven) {
#pragma unroll
            for (int cp = 0; cp < 4; ++cp) {
                unsigned t1 = (cp & 1) ? Bh1b : Bh1a;
                unsigned t2 = (cp & 2) ? Bh2b : Bh2a;
                unsigned r  = (Bu0 ^ t1 ^ t2) & HASHMAP_MASK;
                rlB[cp] = r;
                const i32x2* p = tab + (r & ~1u);
                asm volatile("global_load_dwordx4 %0, %1, off"
                             : "=&v"(pvB[cp]) : "v"(p));
            }
        } else {
#pragma unroll
            for (int c = 0; c < 8; ++c) {
                unsigned t0 = (c & 1) ? (Bu0 + 1u) : Bu0;
                unsigned t1 = (c & 2) ? Bh1b : Bh1a;
                unsigned t2 = (c & 4) ? Bh2b : Bh2a;
                unsigned r  = (t0 ^ t1 ^ t2) & HASHMAP_MASK;
                const i32x2* p = tab + r;
                asm volatile("global_load_dwordx2 %0, %1, off"
                             : "=&v"(qvB[c]) : "v"(p));
            }
        }
    }
    asm volatile("s_waitcnt vmcnt(0)" ::: "memory");
    __builtin_amdgcn_sched_barrier(0);

    float os = scale[0] * (1.0f / 127.0f);

    // ---- phase 2, point A ----
    if (Aeven) {
#pragma unroll
        for (int cp = 0; cp < 4; ++cp) {
            bool swap = (rlA[cp] & 1u) != 0u;
            i32x2 lo; lo.x = pvA[cp].x; lo.y = pvA[cp].y;
            i32x2 hi; hi.x = pvA[cp].z; hi.y = pvA[cp].w;
            qvA[2 * cp + 0] = swap ? hi : lo;
            qvA[2 * cp + 1] = swap ? lo : hi;
        }
    }
    {
        float g0 = 1.0f - Af0, g1 = 1.0f - Af1, g2 = 1.0f - Af2;
        float acc0 = 0.f, acc1 = 0.f, acc2 = 0.f, acc3 = 0.f;
        float acc4 = 0.f, acc5 = 0.f, acc6 = 0.f, acc7 = 0.f;
#pragma unroll
        for (int cp = 0; cp < 4; ++cp) {
            float w12 = ((cp & 1) ? Af1 : g1) * ((cp & 2) ? Af2 : g2);
#pragma unroll
            for (int c0 = 0; c0 < 2; ++c0) {
                float w = w12 * (c0 ? Af0 : g0);
                int a = qvA[2 * cp + c0].x, b = qvA[2 * cp + c0].y;
                acc0 += w * sb(a, 0);  acc1 += w * sb(a, 8);
                acc2 += w * sb(a, 16); acc3 += w * sb(a, 24);
                acc4 += w * sb(b, 0);  acc5 += w * sb(b, 8);
                acc6 += w * sb(b, 16); acc7 += w * sb(b, 24);
            }
        }
        f32x4* o = reinterpret_cast<f32x4*>(out) + (size_t)iA * 2u;
        f32x4 o0 = {acc0 * os, acc1 * os, acc2 * os, acc3 * os};
        f32x4 o1 = {acc4 * os, acc5 * os, acc6 * os, acc7 * os};
        __builtin_nontemporal_store(o0, o);
        __builtin_nontemporal_store(o1, o + 1);
    }

    // ---- phase 2, point B ----
    if (hasB) {
        if (Beven) {
#pragma unroll
            for (int cp = 0; cp < 4; ++cp) {
                bool swap = (rlB[cp] & 1u) != 0u;
                i32x2 lo; lo.x = pvB[cp].x; lo.y = pvB[cp].y;
                i32x2 hi; hi.x = pvB[cp].z; hi.y = pvB[cp].w;
                qvB[2 * cp + 0] = swap ? hi : lo;
                qvB[2 * cp + 1] = swap ? lo : hi;
            }
        }
        float g0 = 1.0f - Bf0, g1 = 1.0f - Bf1, g2 = 1.0f - Bf2;
        float acc0 = 0.f, acc1 = 0.f, acc2 = 0.f, acc3 = 0.f;
        float acc4 = 0.f, acc5 = 0.f, acc6 = 0.f, acc7 = 0.f;
#pragma unroll
        for (int cp = 0; cp < 4; ++cp) {
            float w12 = ((cp & 1) ? Bf1 : g1) * ((cp & 2) ? Bf2 : g2);
#pragma unroll
            for (int c0 = 0; c0 < 2; ++c0) {
                float w = w12 * (c0 ? Bf0 : g0);
                int a = qvB[2 * cp + c0].x, b = qvB[2 * cp + c0].y;
                acc0 += w * sb(a, 0);  acc1 += w * sb(a, 8);
                acc2 += w * sb(a, 16); acc3 += w * sb(a, 24);
                acc4 += w * sb(b, 0);  acc5 += w * sb(b, 8);
                acc6 += w * sb(b, 16); acc7 += w * sb(b, 24);
            }
        }
        f32x4* o = reinterpret_cast<f32x4*>(out) + (size_t)iB * 2u;
        f32x4 o0 = {acc0 * os, acc1 * os, acc2 * os, acc3 * os};
        f32x4 o1 = {acc4 * os, acc5 * os, acc6 * os, acc7 * os};
        __builtin_nontemporal_store(o0, o);
        __builtin_nontemporal_store(o1, o + 1);
    }
}

// ---- fallback: direct fp32 path (if d_ws too small) ----
__global__ __launch_bounds__(256) void hashgrid_fp32_kernel(
    const float* __restrict__ x,
    const float* __restrict__ emb,
    float* __restrict__ out,
    int n)
{
    int i = blockIdx.x * blockDim.x + threadIdx.x;
    if (i >= n) return;

    float x0 = x[i * 3 + 0], x1 = x[i * 3 + 1], x2 = x[i * 3 + 2];
    float xr0 = x0 * RESOLUTION, xr1 = x1 * RESOLUTION, xr2 = x2 * RESOLUTION;
    float fl0 = floorf(xr0), fl1 = floorf(xr1), fl2 = floorf(xr2);
    float f0 = xr0 - fl0, f1 = xr1 - fl1, f2 = xr2 - fl2;
    unsigned u0 = (unsigned)(int)fl0, u1 = (unsigned)(int)fl1, u2 = (unsigned)(int)fl2;

    unsigned h0a = u0,          h0b = u0 + 1u;
    unsigned h1a = u1 * PRIME1, h1b = (u1 + 1u) * PRIME1;
    unsigned h2a = u2 * PRIME2, h2b = (u2 + 1u) * PRIME2;

    float g0 = 1.0f - f0, g1 = 1.0f - f1, g2 = 1.0f - f2;
    float acc0 = 0.f, acc1 = 0.f, acc2 = 0.f, acc3 = 0.f;
    float acc4 = 0.f, acc5 = 0.f, acc6 = 0.f, acc7 = 0.f;

#pragma unroll
    for (int c = 0; c < 8; ++c) {
        unsigned h = (((c & 1) ? h0b : h0a) ^
                      ((c & 2) ? h1b : h1a) ^
                      ((c & 4) ? h2b : h2a)) & HASHMAP_MASK;
        float w = ((c & 1) ? f0 : g0) *
                  ((c & 2) ? f1 : g1) *
                  ((c & 4) ? f2 : g2);
        const float4* e = reinterpret_cast<const float4*>(emb) + (h << 1);
        float4 e0 = e[0];
        float4 e1 = e[1];
        acc0 += w * e0.x; acc1 += w * e0.y; acc2 += w * e0.z; acc3 += w * e0.w;
        acc4 += w * e1.x; acc5 += w * e1.y; acc6 += w * e1.z; acc7 += w * e1.w;
    }

    float4* o = reinterpret_cast<float4*>(out) + (size_t)i * 2u;
    o[0] = make_float4(acc0, acc1, acc2, acc3);
    o[1] = make_float4(acc4, acc5, acc6, acc7);
}

extern "C" void kernel_launch(void* const* d_in, const int* in_sizes, int n_in,
                              void* d_out, int out_size, void* d_ws, size_t ws_size,
                              hipStream_t stream) {
    const float* x   = (const float*)d_in[0];
    const float* emb = (const float*)d_in[1];
    float* out = (float*)d_out;

    int n = in_sizes[0] / 3;  // x has N*3 elements

    // ws layout: [0, 4MB) int8 table | blockmax[1024] | scalef
    size_t tab_bytes = (size_t)HASHMAP_SIZE * 8u;   // 4 MB
    size_t bm_off    = tab_bytes;
    size_t sf_off    = tab_bytes + NRED_BLOCKS * sizeof(float);
    size_t need      = sf_off + sizeof(float);

    if (ws_size >= need) {
        i32x2* tab      = (i32x2*)d_ws;
        float* blockmax = (float*)((char*)d_ws + bm_off);
        float* scalef   = (float*)((char*)d_ws + sf_off);

        absmax_stage1<<<NRED_BLOCKS, 256, 0, stream>>>(emb, blockmax);
        int qgrid = HASHMAP_SIZE / 256;   // 2048
        quantize_fused<<<qgrid, 256, 0, stream>>>(emb, blockmax, tab, scalef);
        int npairs = (n + 1) / 2;
        int ggrid = (npairs + 255) / 256;
        hashgrid_i8_x2<<<ggrid, 256, 0, stream>>>(x, tab, scalef, out, n);
    } else {
        int grid = (n + 255) / 256;
        hashgrid_fp32_kernel<<<grid, 256, 0, stream>>>(x, emb, out, n);
    }
}

// Round 18
// 77.369 us; speedup vs baseline: 1.2528x; 1.2500x over previous
//
#include <hip/hip_runtime.h>

// Instant-NGP style hash grid interpolation.
// x: [N, 3] f32 in [0,1), emb: [524288, 8] f32, out: [N, 8] f32.
//
// Round 18: restore R14 (session best, 77.2us) verbatim.
// Final model: gather is bound by aggregate L2 random-line read BW
// (~12-13 TB/s across R1/R5/R6/R8 table formats). R8/R14's scheme touches
// 6 x 64B lines/point (even-u0: 4 pair lines, odd-u0: 8 row lines) -> floor
// ~59us; measured 64.8us = 92% of the wall. Further line cuts are blocked:
// 4-bit quant error (0.039) >> threshold (0.0084); only dim-0 (prime=1)
// yields pair adjacency. 2-pt/thread MLP raise is un-compilable without
// scratch demotion (R15/R16/R17). Prep is ~12us vs ~8us floor.

#define HASHMAP_SIZE 524288
#define HASHMAP_MASK 524287u   // 2^19 - 1
#define RESOLUTION   128.0f
#define PRIME1       2654435761u
#define PRIME2       805459861u

typedef float f32x4 __attribute__((ext_vector_type(4)));
typedef int   i32x2 __attribute__((ext_vector_type(2)));
typedef int   i32x4 __attribute__((ext_vector_type(4)));

#define NRED_BLOCKS 1024   // stage1 grid; 1024*256*4 float4 == 16MB exactly

__device__ __forceinline__ int pack4(float4 v, float rs) {
    int b0 = __float2int_rn(v.x * rs), b1 = __float2int_rn(v.y * rs);
    int b2 = __float2int_rn(v.z * rs), b3 = __float2int_rn(v.w * rs);
    return (int)((b0 & 0xff) | ((b1 & 0xff) << 8) |
                 ((b2 & 0xff) << 16) | ((unsigned)b3 << 24));
}

// ---- stage 1: per-block absmax over emb (one exact pass, 4 f32x4/thread) ----
__global__ __launch_bounds__(256) void absmax_stage1(
    const float* __restrict__ emb, float* __restrict__ blockmax)
{
    __shared__ float sm[256];
    int tid = threadIdx.x;
    int t = blockIdx.x * 256 + tid;
    const f32x4* e4 = reinterpret_cast<const f32x4*>(emb);
    float m = 0.f;
#pragma unroll
    for (int k = 0; k < 4; ++k) {
        f32x4 v = e4[t + k * (NRED_BLOCKS * 256)];
        m = fmaxf(m, fmaxf(fmaxf(fabsf(v.x), fabsf(v.y)),
                           fmaxf(fabsf(v.z), fabsf(v.w))));
    }
    sm[tid] = m;
    __syncthreads();
    for (int s = 128; s > 0; s >>= 1) {
        if (tid < s) sm[tid] = fmaxf(sm[tid], sm[tid + s]);
        __syncthreads();
    }
    if (tid == 0) blockmax[blockIdx.x] = sm[0];
}

// ---- quantize (+ final reduce of 1024 partials): f32 rows -> int8 rows ----
__global__ __launch_bounds__(256) void quantize_fused(
    const float* __restrict__ emb, const float* __restrict__ blockmax,
    i32x2* __restrict__ tab, float* __restrict__ scalef)
{
    __shared__ float sm[256];
    int tid = threadIdx.x;
    float m = fmaxf(fmaxf(blockmax[tid],       blockmax[tid + 256]),
                    fmaxf(blockmax[tid + 512], blockmax[tid + 768]));
    sm[tid] = m;
    __syncthreads();
    for (int s = 128; s > 0; s >>= 1) {
        if (tid < s) sm[tid] = fmaxf(sm[tid], sm[tid + s]);
        __syncthreads();
    }
    float sc = (sm[0] > 0.f) ? sm[0] : 1.0f;
    if (blockIdx.x == 0 && tid == 0) scalef[0] = sc;

    int r = blockIdx.x * 256 + tid;
    if (r >= HASHMAP_SIZE) return;
    float rs = 127.0f / sc;
    const float4* src = reinterpret_cast<const float4*>(emb) + 2 * r;
    i32x2 o;
    o.x = pack4(src[0], rs);
    o.y = pack4(src[1], rs);
    __builtin_nontemporal_store(o, &tab[r]);   // clean lines -> L3, not dirty L2
}

__device__ __forceinline__ float sb(int v, int sh) {
    // sign-extended byte -> float
    return (float)((int)((unsigned)v << (24 - sh)) >> 24);
}

// ---- gather: corner-pair merge, divergent even/odd paths (R8 structure) ----
__global__ __launch_bounds__(256) void hashgrid_i8_kernel(
    const float* __restrict__ x,
    const i32x2* __restrict__ tab,
    const float* __restrict__ scale,
    float* __restrict__ out,
    int n)
{
    int i = blockIdx.x * blockDim.x + threadIdx.x;
    if (i >= n) return;

    float x0 = __builtin_nontemporal_load(x + 3 * i + 0);
    float x1 = __builtin_nontemporal_load(x + 3 * i + 1);
    float x2 = __builtin_nontemporal_load(x + 3 * i + 2);

    float xr0 = x0 * RESOLUTION;
    float xr1 = x1 * RESOLUTION;
    float xr2 = x2 * RESOLUTION;

    float fl0 = floorf(xr0);
    float fl1 = floorf(xr1);
    float fl2 = floorf(xr2);

    float f0 = xr0 - fl0;
    float f1 = xr1 - fl1;
    float f2 = xr2 - fl2;

    unsigned u0 = (unsigned)(int)fl0;
    unsigned u1 = (unsigned)(int)fl1;
    unsigned u2 = (unsigned)(int)fl2;

    unsigned h1a = u1 * PRIME1, h1b = (u1 + 1u) * PRIME1;
    unsigned h2a = u2 * PRIME2, h2b = (u2 + 1u) * PRIME2;

    bool even = ((u0 & 1u) == 0u);

    // Phase 1: issue ALL loads (both divergent halves) before one waitcnt.
    i32x2 qv[8];
    i32x4 pv[4];
    unsigned rl[4];
    if (even) {
        // 4 pair-loads: rows r and r^1 live in one aligned 16B pair.
#pragma unroll
        for (int cp = 0; cp < 4; ++cp) {
            unsigned t1 = (cp & 1) ? h1b : h1a;
            unsigned t2 = (cp & 2) ? h2b : h2a;
            unsigned r  = (u0 ^ t1 ^ t2) & HASHMAP_MASK;
            rl[cp] = r;
            const i32x2* p = tab + (r & ~1u);
            asm volatile("global_load_dwordx4 %0, %1, off"
                         : "=&v"(pv[cp]) : "v"(p));
        }
    } else {
        // 8 single-row loads.
#pragma unroll
        for (int c = 0; c < 8; ++c) {
            unsigned t0 = (c & 1) ? (u0 + 1u) : u0;
            unsigned t1 = (c & 2) ? h1b : h1a;
            unsigned t2 = (c & 4) ? h2b : h2a;
            unsigned r  = (t0 ^ t1 ^ t2) & HASHMAP_MASK;
            const i32x2* p = tab + r;
            asm volatile("global_load_dwordx2 %0, %1, off"
                         : "=&v"(qv[c]) : "v"(p));
        }
    }
    asm volatile("s_waitcnt vmcnt(0)" ::: "memory");
    __builtin_amdgcn_sched_barrier(0);

    // Unpack pairs (even lanes only — must not clobber odd lanes' qv).
    if (even) {
#pragma unroll
        for (int cp = 0; cp < 4; ++cp) {
            bool swap = (rl[cp] & 1u) != 0u;  // r odd -> t0=u0 row is HIGH half
            i32x2 lo; lo.x = pv[cp].x; lo.y = pv[cp].y;
            i32x2 hi; hi.x = pv[cp].z; hi.y = pv[cp].w;
            qv[2 * cp + 0] = swap ? hi : lo;   // corner with t0 = u0
            qv[2 * cp + 1] = swap ? lo : hi;   // corner with t0 = u0+1
        }
    }

    // Phase 2: trilinear weights + accumulate.
    float g0 = 1.0f - f0;
    float g1 = 1.0f - f1;
    float g2 = 1.0f - f2;

    float acc0 = 0.f, acc1 = 0.f, acc2 = 0.f, acc3 = 0.f;
    float acc4 = 0.f, acc5 = 0.f, acc6 = 0.f, acc7 = 0.f;

#pragma unroll
    for (int cp = 0; cp < 4; ++cp) {
        float w12 = ((cp & 1) ? f1 : g1) * ((cp & 2) ? f2 : g2);
#pragma unroll
        for (int c0 = 0; c0 < 2; ++c0) {
            float w = w12 * (c0 ? f0 : g0);
            int a = qv[2 * cp + c0].x, b = qv[2 * cp + c0].y;
            acc0 += w * sb(a, 0);  acc1 += w * sb(a, 8);
            acc2 += w * sb(a, 16); acc3 += w * sb(a, 24);
            acc4 += w * sb(b, 0);  acc5 += w * sb(b, 8);
            acc6 += w * sb(b, 16); acc7 += w * sb(b, 24);
        }
    }

    float os = scale[0] * (1.0f / 127.0f);  // uniform L2-hit load
    f32x4* o = reinterpret_cast<f32x4*>(out) + (size_t)i * 2u;
    f32x4 o0 = {acc0 * os, acc1 * os, acc2 * os, acc3 * os};
    f32x4 o1 = {acc4 * os, acc5 * os, acc6 * os, acc7 * os};
    __builtin_nontemporal_store(o0, o);
    __builtin_nontemporal_store(o1, o + 1);
}

// ---- fallback: direct fp32 path (if d_ws too small) ----
__global__ __launch_bounds__(256) void hashgrid_fp32_kernel(
    const float* __restrict__ x,
    const float* __restrict__ emb,
    float* __restrict__ out,
    int n)
{
    int i = blockIdx.x * blockDim.x + threadIdx.x;
    if (i >= n) return;

    float x0 = x[i * 3 + 0], x1 = x[i * 3 + 1], x2 = x[i * 3 + 2];
    float xr0 = x0 * RESOLUTION, xr1 = x1 * RESOLUTION, xr2 = x2 * RESOLUTION;
    float fl0 = floorf(xr0), fl1 = floorf(xr1), fl2 = floorf(xr2);
    float f0 = xr0 - fl0, f1 = xr1 - fl1, f2 = xr2 - fl2;
    unsigned u0 = (unsigned)(int)fl0, u1 = (unsigned)(int)fl1, u2 = (unsigned)(int)fl2;

    unsigned h0a = u0,          h0b = u0 + 1u;
    unsigned h1a = u1 * PRIME1, h1b = (u1 + 1u) * PRIME1;
    unsigned h2a = u2 * PRIME2, h2b = (u2 + 1u) * PRIME2;

    float g0 = 1.0f - f0, g1 = 1.0f - f1, g2 = 1.0f - f2;
    float acc0 = 0.f, acc1 = 0.f, acc2 = 0.f, acc3 = 0.f;
    float acc4 = 0.f, acc5 = 0.f, acc6 = 0.f, acc7 = 0.f;

#pragma unroll
    for (int c = 0; c < 8; ++c) {
        unsigned h = (((c & 1) ? h0b : h0a) ^
                      ((c & 2) ? h1b : h1a) ^
                      ((c & 4) ? h2b : h2a)) & HASHMAP_MASK;
        float w = ((c & 1) ? f0 : g0) *
                  ((c & 2) ? f1 : g1) *
                  ((c & 4) ? f2 : g2);
        const float4* e = reinterpret_cast<const float4*>(emb) + (h << 1);
        float4 e0 = e[0];
        float4 e1 = e[1];
        acc0 += w * e0.x; acc1 += w * e0.y; acc2 += w * e0.z; acc3 += w * e0.w;
        acc4 += w * e1.x; acc5 += w * e1.y; acc6 += w * e1.z; acc7 += w * e1.w;
    }

    float4* o = reinterpret_cast<float4*>(out) + (size_t)i * 2u;
    o[0] = make_float4(acc0, acc1, acc2, acc3);
    o[1] = make_float4(acc4, acc5, acc6, acc7);
}

extern "C" void kernel_launch(void* const* d_in, const int* in_sizes, int n_in,
                              void* d_out, int out_size, void* d_ws, size_t ws_size,
                              hipStream_t stream) {
    const float* x   = (const float*)d_in[0];
    const float* emb = (const float*)d_in[1];
    float* out = (float*)d_out;

    int n = in_sizes[0] / 3;  // x has N*3 elements
    int block = 256;
    int grid = (n + block - 1) / block;

    // ws layout: [0, 4MB) int8 table | blockmax[1024] | scalef
    size_t tab_bytes = (size_t)HASHMAP_SIZE * 8u;   // 4 MB
    size_t bm_off    = tab_bytes;
    size_t sf_off    = tab_bytes + NRED_BLOCKS * sizeof(float);
    size_t need      = sf_off + sizeof(float);

    if (ws_size >= need) {
        i32x2* tab      = (i32x2*)d_ws;
        float* blockmax = (float*)((char*)d_ws + bm_off);
        float* scalef   = (float*)((char*)d_ws + sf_off);

        absmax_stage1<<<NRED_BLOCKS, 256, 0, stream>>>(emb, blockmax);
        int qgrid = HASHMAP_SIZE / 256;   // 2048
        quantize_fused<<<qgrid, 256, 0, stream>>>(emb, blockmax, tab, scalef);
        hashgrid_i8_kernel<<<grid, block, 0, stream>>>(x, tab, scalef, out, n);
    } else {
        hashgrid_fp32_kernel<<<grid, block, 0, stream>>>(x, emb, out, n);
    }
}